// Round 2
// baseline (1849.533 us; speedup 1.0000x reference)
//
#include <hip/hip_runtime.h>
#include <math.h>

#define EPSF 1e-5f

// ---- problem dims ----
#define NROW   32768   // B*H*W image tokens (all GEMMs run in image layout)
#define CDIM   384
#define N3     1152
#define FFDIM  1536

__device__ __forceinline__ float gelu_exact(float v) {
    return 0.5f * v * (1.f + erff(v * 0.70710678118654752f));
}

// ---------------- padvec: qkv row of a zero-padded token ----------------
// reference pads x with zeros BEFORE ln1 -> LN(0-row) = ln1_b -> qkv row =
// ln1_b @ qkv_w + qkv_b. Padded slots contribute this to window softmax.
__global__ __launch_bounds__(256) void padvec_kernel(
    const float* __restrict__ ln1_b, const float* __restrict__ qkv_w,
    const float* __restrict__ qkv_b, float* __restrict__ padvec)
{
    int j = blockIdx.x * 256 + threadIdx.x;
    if (j >= N3) return;
    float acc = qkv_b[j];
    for (int k = 0; k < CDIM; ++k) acc = fmaf(ln1_b[k], qkv_w[k * N3 + j], acc);
    padvec[j] = acc;
}

// ---------------- LN row stats (mu, rsigma), one wave per row ----------------
__global__ __launch_bounds__(256) void ln_stats_kernel(const float* __restrict__ src,
                                                       float2* __restrict__ stats) {
    int row  = (int)((blockIdx.x * blockDim.x + threadIdx.x) >> 6);
    int lane = threadIdx.x & 63;
    const float* p = src + (size_t)row * CDIM;
    float s1 = 0.f, s2 = 0.f;
    for (int k = lane; k < CDIM; k += 64) { float v = p[k]; s1 += v; s2 += v * v; }
    #pragma unroll
    for (int off = 32; off > 0; off >>= 1) {
        s1 += __shfl_down(s1, off);
        s2 += __shfl_down(s2, off);
    }
    if (lane == 0) {
        float mu  = s1 * (1.f / CDIM);
        float var = s2 * (1.f / CDIM) - mu * mu;
        stats[row] = make_float2(mu, rsqrtf(var + EPSF));
    }
}

// ---------------- fp32 GEMM, 128x128x8 tile, 8x8/thread, M=32768 ----------------
// LNA: apply (a-mu)*rs*lnw+lnb to A rows.  EPI: 0=store, 1=gelu+store, 2=resid+store
template<bool LNA, int EPI, int KD>
__global__ __launch_bounds__(256) void gemm_kernel(
    const float* __restrict__ A, const float* __restrict__ Bw,
    const float* __restrict__ bias, float* __restrict__ out,
    const float2* __restrict__ stats, const float* __restrict__ lnw,
    const float* __restrict__ lnb, const float* __restrict__ resid,
    int Nn)
{
    __shared__ float As[8][128];
    __shared__ float Bs[8][128];
    const int tid = threadIdx.x;
    const int bn0 = blockIdx.x * 128;
    const int bm0 = blockIdx.y * 128;

    // A staging: thread owns tile-row (tid>>1), k-quad (tid&1)*4
    const int am = tid >> 1;
    const int ak = (tid & 1) * 4;
    const int gRow = bm0 + am;
    const float* aRow = A + (size_t)gRow * KD;
    float mu = 0.f, rs = 0.f;
    if (LNA) { float2 st = stats[gRow]; mu = st.x; rs = st.y; }

    // B staging: thread owns k-row (tid>>5), col-quad (tid&31)*4
    const int bk = tid >> 5;
    const int bq = (tid & 31) * 4;

    const int tm = (tid >> 4) * 8;
    const int tn = (tid & 15) * 8;

    float acc[8][8] = {};

    for (int kt = 0; kt < KD; kt += 8) {
        float4 av = *(const float4*)(aRow + kt + ak);
        if (LNA) {
            float4 gv = *(const float4*)(lnw + kt + ak);
            float4 bv = *(const float4*)(lnb + kt + ak);
            av.x = (av.x - mu) * rs * gv.x + bv.x;
            av.y = (av.y - mu) * rs * gv.y + bv.y;
            av.z = (av.z - mu) * rs * gv.z + bv.z;
            av.w = (av.w - mu) * rs * gv.w + bv.w;
        }
        As[ak + 0][am] = av.x;
        As[ak + 1][am] = av.y;
        As[ak + 2][am] = av.z;
        As[ak + 3][am] = av.w;
        *(float4*)&Bs[bk][bq] = *(const float4*)(Bw + (size_t)(kt + bk) * Nn + bn0 + bq);
        __syncthreads();
        #pragma unroll
        for (int kk = 0; kk < 8; ++kk) {
            float a[8], b[8];
            *(float4*)&a[0] = *(float4*)&As[kk][tm];
            *(float4*)&a[4] = *(float4*)&As[kk][tm + 4];
            *(float4*)&b[0] = *(float4*)&Bs[kk][tn];
            *(float4*)&b[4] = *(float4*)&Bs[kk][tn + 4];
            #pragma unroll
            for (int i = 0; i < 8; ++i)
                #pragma unroll
                for (int j = 0; j < 8; ++j)
                    acc[i][j] = fmaf(a[i], b[j], acc[i][j]);
        }
        __syncthreads();
    }

    float4 bb0 = *(const float4*)(bias + bn0 + tn);
    float4 bb1 = *(const float4*)(bias + bn0 + tn + 4);

    #pragma unroll
    for (int i = 0; i < 8; ++i) {
        int rm = bm0 + tm + i;
        float4 v0, v1;
        v0.x = acc[i][0] + bb0.x; v0.y = acc[i][1] + bb0.y;
        v0.z = acc[i][2] + bb0.z; v0.w = acc[i][3] + bb0.w;
        v1.x = acc[i][4] + bb1.x; v1.y = acc[i][5] + bb1.y;
        v1.z = acc[i][6] + bb1.z; v1.w = acc[i][7] + bb1.w;

        if (EPI == 1) {
            v0.x = gelu_exact(v0.x); v0.y = gelu_exact(v0.y);
            v0.z = gelu_exact(v0.z); v0.w = gelu_exact(v0.w);
            v1.x = gelu_exact(v1.x); v1.y = gelu_exact(v1.y);
            v1.z = gelu_exact(v1.z); v1.w = gelu_exact(v1.w);
        }
        size_t off = (size_t)rm * Nn + bn0 + tn;
        if (EPI == 2) {
            float4 r0 = *(const float4*)(resid + off);
            float4 r1 = *(const float4*)(resid + off + 4);
            v0.x += r0.x; v0.y += r0.y; v0.z += r0.z; v0.w += r0.w;
            v1.x += r1.x; v1.y += r1.y; v1.z += r1.z; v1.w += r1.w;
        }
        *(float4*)(out + off) = v0;
        *(float4*)(out + off + 4) = v1;
    }
}

// ---------------- window attention: one block per (window, head) ----------------
// qkv is in IMAGE layout (32768 x 1152); window gather (incl. pad slots via
// padvec) happens at the LDS load; output scattered back to image layout.
__global__ __launch_bounds__(256) void attn_kernel(
    const float* __restrict__ qkv, const float* __restrict__ padvec,
    const float* __restrict__ attn_bias, const int* __restrict__ bias_idxs,
    float* __restrict__ o)
{
    const int w = blockIdx.x / 12;     // window 0..799
    const int h = blockIdx.x % 12;     // head
    __shared__ float q[49][33], k[49][33], v[49][33];  // stride 33: no bank conflict
    __shared__ float s[49][49];
    __shared__ float brow[49];
    __shared__ int   simg[49];
    const int tid = threadIdx.x;

    if (tid < 49) {
        int b  = w / 25, wi = w % 25;
        int gh = (wi / 5) * 7 + tid / 7;
        int gw = (wi % 5) * 7 + tid % 7;
        simg[tid] = (gh < 32 && gw < 32) ? (b * 1024 + gh * 32 + gw) : -1;
        brow[tid] = attn_bias[h * 49 + tid];
    }
    __syncthreads();

    for (int e = tid; e < 49 * 32; e += 256) {
        int n = e >> 5, d = e & 31;
        int si = simg[n];
        const float* p = (si >= 0) ? (qkv + (size_t)si * N3 + h * 96 + d)
                                   : (padvec + h * 96 + d);
        q[n][d] = p[0];
        k[n][d] = p[32];
        v[n][d] = p[64];
    }
    __syncthreads();

    for (int e = tid; e < 49 * 49; e += 256) {
        int n = e / 49, m = e % 49;
        float acc = 0.f;
        #pragma unroll
        for (int d = 0; d < 32; ++d) acc = fmaf(q[n][d], k[m][d], acc);
        s[n][m] = acc * 0.17677669529663687f + brow[bias_idxs[e]];
    }
    __syncthreads();

    if (tid < 49) {
        float mx = -1e30f;
        for (int m = 0; m < 49; ++m) mx = fmaxf(mx, s[tid][m]);
        float sum = 0.f;
        for (int m = 0; m < 49; ++m) { float e2 = expf(s[tid][m] - mx); s[tid][m] = e2; sum += e2; }
        float inv = 1.f / sum;
        for (int m = 0; m < 49; ++m) s[tid][m] *= inv;
    }
    __syncthreads();

    for (int e = tid; e < 49 * 32; e += 256) {
        int n = e >> 5, d = e & 31;
        int si = simg[n];
        if (si < 0) continue;          // padded slot output is discarded
        float acc = 0.f;
        for (int m = 0; m < 49; ++m) acc = fmaf(s[n][m], v[m][d], acc);
        o[(size_t)si * CDIM + h * 32 + d] = acc;
    }
}

// ---------------- depthwise 3x3 conv (channels-last) + BN ----------------
__global__ __launch_bounds__(256) void conv_bn_kernel(
    const float* __restrict__ xin, const float* __restrict__ cw,
    const float* __restrict__ bn_g, const float* __restrict__ bn_b,
    const float* __restrict__ bn_m, const float* __restrict__ bn_v,
    float* __restrict__ xout)
{
    __shared__ float wsm[9 * 384];  // transposed [tap][channel]
    for (int i = threadIdx.x; i < 9 * 384; i += 256) {
        int c = i / 9, wi = i % 9;
        wsm[wi * 384 + c] = cw[i];
    }
    __syncthreads();

    int gid = blockIdx.x * 256 + threadIdx.x;   // 32*32*32*96 exactly
    int c4 = gid % 96;
    int t  = gid / 96;
    int w  = t % 32; t /= 32;
    int h  = t % 32;
    int b  = t / 32;
    int c0 = c4 * 4;

    float4 acc = make_float4(0.f, 0.f, 0.f, 0.f);
    #pragma unroll
    for (int dh = -1; dh <= 1; ++dh) {
        int hh = h + dh;
        if (hh < 0 || hh >= 32) continue;
        #pragma unroll
        for (int dw = -1; dw <= 1; ++dw) {
            int ww = w + dw;
            if (ww < 0 || ww >= 32) continue;
            float4 xv = *(const float4*)(xin + ((size_t)(b * 1024 + hh * 32 + ww)) * CDIM + c0);
            float4 wv = *(const float4*)&wsm[((dh + 1) * 3 + (dw + 1)) * 384 + c0];
            acc.x = fmaf(xv.x, wv.x, acc.x);
            acc.y = fmaf(xv.y, wv.y, acc.y);
            acc.z = fmaf(xv.z, wv.z, acc.z);
            acc.w = fmaf(xv.w, wv.w, acc.w);
        }
    }
    float4 o;
    float sc;
    sc = rsqrtf(bn_v[c0 + 0] + EPSF) * bn_g[c0 + 0]; o.x = (acc.x - bn_m[c0 + 0]) * sc + bn_b[c0 + 0];
    sc = rsqrtf(bn_v[c0 + 1] + EPSF) * bn_g[c0 + 1]; o.y = (acc.y - bn_m[c0 + 1]) * sc + bn_b[c0 + 1];
    sc = rsqrtf(bn_v[c0 + 2] + EPSF) * bn_g[c0 + 2]; o.z = (acc.z - bn_m[c0 + 2]) * sc + bn_b[c0 + 2];
    sc = rsqrtf(bn_v[c0 + 3] + EPSF) * bn_g[c0 + 3]; o.w = (acc.w - bn_m[c0 + 3]) * sc + bn_b[c0 + 3];
    *(float4*)(xout + (size_t)gid * 4) = o;
}

// ---------------- launch ----------------
extern "C" void kernel_launch(void* const* d_in, const int* in_sizes, int n_in,
                              void* d_out, int out_size, void* d_ws, size_t ws_size,
                              hipStream_t stream) {
    const float* x         = (const float*)d_in[0];
    const float* ln1_w     = (const float*)d_in[1];
    const float* ln1_b     = (const float*)d_in[2];
    const float* qkv_w     = (const float*)d_in[3];
    const float* qkv_b     = (const float*)d_in[4];
    const float* proj_w    = (const float*)d_in[5];
    const float* proj_b    = (const float*)d_in[6];
    const float* attn_bias = (const float*)d_in[7];
    const int*   bias_idxs = (const int*)d_in[8];
    const float* conv_w    = (const float*)d_in[9];
    const float* bn_g      = (const float*)d_in[10];
    const float* bn_b      = (const float*)d_in[11];
    const float* bn_m      = (const float*)d_in[12];
    const float* bn_v      = (const float*)d_in[13];
    const float* ln2_w     = (const float*)d_in[14];
    const float* ln2_b     = (const float*)d_in[15];
    const float* fc1_w     = (const float*)d_in[16];
    const float* fc1_b     = (const float*)d_in[17];
    const float* fc2_w     = (const float*)d_in[18];
    const float* fc2_b     = (const float*)d_in[19];
    float* out = (float*)d_out;

    // workspace: 201,855,488 B (~193 MB) with lifetime overlays
    //   region A [0, 201.3MB): qkv_img (st2-3) -> x1 (st4-5) -> hbuf (st7-8)
    //   o_img    [151.0, 201.3MB): (st3-4, dead before hbuf fills)
    //   x2 lives in d_out (conv writes, fc1/fc2 read, fc2 rewrites in place)
    char* ws = (char*)d_ws;
    float*  qkvb  = (float*)(ws + 0);              // 32768*1152*4 = 150,994,944
    float*  x1    = (float*)(ws + 0);              // 32768*384*4  =  50,331,648
    float*  hbuf  = (float*)(ws + 0);              // 32768*1536*4 = 201,326,592
    float*  oimg  = (float*)(ws + 150994944ULL);   // 32768*384*4  =  50,331,648
    float2* st1   = (float2*)(ws + 201326592ULL);  // 262,144
    float2* st2   = (float2*)(ws + 201588736ULL);  // 262,144
    float*  pvec  = (float*)(ws + 201850880ULL);   // 4,608

    // 1) pad-slot qkv row
    padvec_kernel<<<5, 256, 0, stream>>>(ln1_b, qkv_w, qkv_b, pvec);
    // 2) LN1 stats on image rows
    ln_stats_kernel<<<8192, 256, 0, stream>>>(x, st1);
    // 3) qkv = LN1(x) @ qkv_w + qkv_b   (image layout)
    gemm_kernel<true, 0, 384><<<dim3(9, 256), 256, 0, stream>>>(
        x, qkv_w, qkv_b, qkvb, st1, ln1_w, ln1_b, nullptr, N3);
    // 4) windowed attention (gather from image, scatter to image)
    attn_kernel<<<9600, 256, 0, stream>>>(qkvb, pvec, attn_bias, bias_idxs, oimg);
    // 5) x1 = x + o @ proj_w + proj_b
    gemm_kernel<false, 2, 384><<<dim3(3, 256), 256, 0, stream>>>(
        oimg, proj_w, proj_b, x1, nullptr, nullptr, nullptr, x, CDIM);
    // 6) x2(=d_out) = BN(dwconv3x3(x1))
    conv_bn_kernel<<<12288, 256, 0, stream>>>(x1, conv_w, bn_g, bn_b, bn_m, bn_v, out);
    // 7) LN2 stats on x2
    ln_stats_kernel<<<8192, 256, 0, stream>>>(out, st2);
    // 8) h = gelu(LN2(x2) @ fc1_w + fc1_b)
    gemm_kernel<true, 1, 384><<<dim3(12, 256), 256, 0, stream>>>(
        out, fc1_w, fc1_b, hbuf, st2, ln2_w, ln2_b, nullptr, FFDIM);
    // 9) out = x2 + h @ fc2_w + fc2_b   (in place over d_out)
    gemm_kernel<false, 2, 1536><<<dim3(3, 256), 256, 0, stream>>>(
        hbuf, fc2_w, fc2_b, out, nullptr, nullptr, nullptr, out, CDIM);
}

// Round 3
// 682.993 us; speedup vs baseline: 2.7080x; 2.7080x over previous
//
#include <hip/hip_runtime.h>
#include <math.h>

#define EPSF 1e-5f

// ---- problem dims ----
#define NROW   32768   // B*H*W image tokens
#define CDIM   384
#define N3     1152
#define FFDIM  1536

typedef unsigned short ushort_t;
typedef __attribute__((ext_vector_type(8))) short short8v;   // 8 bf16 (4 VGPRs)
typedef __attribute__((ext_vector_type(4))) float f32x4;     // MFMA accumulator

__device__ __forceinline__ float gelu_exact(float v) {
    return 0.5f * v * (1.f + erff(v * 0.70710678118654752f));
}

// fp32 -> bf16 round-to-nearest-even
__device__ __forceinline__ ushort_t f2bf(float f) {
    union { float f; unsigned u; } v; v.f = f;
    unsigned r = v.u + 0x7fffu + ((v.u >> 16) & 1u);
    return (ushort_t)(r >> 16);
}

// ---------------- weight transpose + bf16 convert: W[K][N] -> Wt[N][K] ----------------
__global__ __launch_bounds__(256) void wt_bf16_kernel(const float* __restrict__ W,
                                                      ushort_t* __restrict__ Wt,
                                                      int K, int N) {
    __shared__ float t[32][33];
    const int bx = blockIdx.x, by = blockIdx.y;       // n-tile, k-tile
    const int c = threadIdx.x & 31, r0 = threadIdx.x >> 5;
    #pragma unroll
    for (int i = 0; i < 4; ++i) {
        int r = r0 + i * 8;
        t[r][c] = W[(size_t)(by * 32 + r) * N + bx * 32 + c];
    }
    __syncthreads();
    #pragma unroll
    for (int i = 0; i < 4; ++i) {
        int r = r0 + i * 8;
        Wt[(size_t)(bx * 32 + r) * K + by * 32 + c] = f2bf(t[c][r]);
    }
}

// ---------------- padvec: qkv row of a zero-padded token (fp32) ----------------
__global__ __launch_bounds__(256) void padvec_kernel(
    const float* __restrict__ ln1_b, const float* __restrict__ qkv_w,
    const float* __restrict__ qkv_b, float* __restrict__ padvec)
{
    int j = blockIdx.x * 256 + threadIdx.x;
    if (j >= N3) return;
    float acc = qkv_b[j];
    for (int k = 0; k < CDIM; ++k) acc = fmaf(ln1_b[k], qkv_w[k * N3 + j], acc);
    padvec[j] = acc;
}

// ---------------- fused LN (stats + normalize) -> bf16 rows, one wave/row ----------------
__global__ __launch_bounds__(256) void ln_bf16_kernel(
    const float* __restrict__ src, const float* __restrict__ w,
    const float* __restrict__ b, ushort_t* __restrict__ dst)
{
    const int row  = blockIdx.x * 4 + (threadIdx.x >> 6);
    const int lane = threadIdx.x & 63;
    const float* p = src + (size_t)row * CDIM;
    float vals[6];
    float s1 = 0.f, s2 = 0.f;
    #pragma unroll
    for (int i = 0; i < 6; ++i) {
        float v = p[lane + 64 * i];
        vals[i] = v; s1 += v; s2 += v * v;
    }
    #pragma unroll
    for (int off = 32; off > 0; off >>= 1) {
        s1 += __shfl_xor(s1, off);
        s2 += __shfl_xor(s2, off);
    }
    float mu = s1 * (1.f / CDIM);
    float rs = rsqrtf(s2 * (1.f / CDIM) - mu * mu + EPSF);
    ushort_t* q = dst + (size_t)row * CDIM;
    #pragma unroll
    for (int i = 0; i < 6; ++i) {
        int k = lane + 64 * i;
        q[k] = f2bf((vals[i] - mu) * rs * w[k] + b[k]);
    }
}

// ---------------- bf16 MFMA GEMM: C = A[M][K] @ Bt[N][K]^T, 128x128 tile ----------------
// EPI: 0 = +bias, fp32 store (qkv)
//      1 = +bias, gelu, bf16 store (fc1)
//      2 = +bias, +resid, fp32 store (proj, fc2)
template<int EPI>
__global__ __launch_bounds__(256) void gemm_bf16_kernel(
    const ushort_t* __restrict__ A, const ushort_t* __restrict__ Bt,
    const float* __restrict__ bias, void* __restrict__ outv,
    const float* __restrict__ resid, int Nn, int K)
{
    __shared__ ushort_t As[128][72];   // +8 pad: 144B row stride -> worst 2-way bank alias
    __shared__ ushort_t Bs[128][72];
    const int tid  = threadIdx.x;
    const int lane = tid & 63;
    const int wv   = tid >> 6;
    const int wm   = (wv & 1) * 64, wn = (wv >> 1) * 64;
    const int bn0  = blockIdx.x * 128, bm0 = blockIdx.y * 128;

    const int srow = tid >> 3;     // staging: base row 0..31
    const int skc  = tid & 7;      // 16B chunk within row (8 bf16)

    f32x4 acc[4][4] = {};

    const int cl = lane & 15;
    const int kq = (lane >> 4) * 8;

    for (int kt = 0; kt < K; kt += 64) {
        if (kt) __syncthreads();
        #pragma unroll
        for (int i = 0; i < 4; ++i) {
            int row = srow + i * 32;
            *(float4*)&As[row][skc * 8] =
                *(const float4*)(A  + (size_t)(bm0 + row) * K + kt + skc * 8);
            *(float4*)&Bs[row][skc * 8] =
                *(const float4*)(Bt + (size_t)(bn0 + row) * K + kt + skc * 8);
        }
        __syncthreads();
        #pragma unroll
        for (int kb = 0; kb < 2; ++kb) {
            const int ko = kb * 32 + kq;
            short8v a[4], b[4];
            #pragma unroll
            for (int mi = 0; mi < 4; ++mi)
                a[mi] = *(const short8v*)&As[wm + mi * 16 + cl][ko];
            #pragma unroll
            for (int ni = 0; ni < 4; ++ni)
                b[ni] = *(const short8v*)&Bs[wn + ni * 16 + cl][ko];
            #pragma unroll
            for (int mi = 0; mi < 4; ++mi)
                #pragma unroll
                for (int ni = 0; ni < 4; ++ni)
                    acc[mi][ni] = __builtin_amdgcn_mfma_f32_16x16x32_bf16(
                        a[mi], b[ni], acc[mi][ni], 0, 0, 0);
        }
    }

    // epilogue: D col = lane&15, row = (lane>>4)*4 + reg
    const int rq = (lane >> 4) * 4;
    #pragma unroll
    for (int ni = 0; ni < 4; ++ni) {
        const int col = bn0 + wn + ni * 16 + cl;
        const float bs = bias[col];
        #pragma unroll
        for (int mi = 0; mi < 4; ++mi) {
            const int row = bm0 + wm + mi * 16 + rq;
            #pragma unroll
            for (int r = 0; r < 4; ++r) {
                float v = acc[mi][ni][r] + bs;
                size_t off = (size_t)(row + r) * Nn + col;
                if (EPI == 0) {
                    ((float*)outv)[off] = v;
                } else if (EPI == 1) {
                    ((ushort_t*)outv)[off] = f2bf(gelu_exact(v));
                } else {
                    ((float*)outv)[off] = v + resid[off];
                }
            }
        }
    }
}

// ---------------- window attention: one block per (window, head) ----------------
// qkv fp32 image layout; gather (pad slots via padvec) at LDS load; bf16 output.
__global__ __launch_bounds__(256) void attn_kernel(
    const float* __restrict__ qkv, const float* __restrict__ padvec,
    const float* __restrict__ attn_bias, const int* __restrict__ bias_idxs,
    ushort_t* __restrict__ o)
{
    const int w = blockIdx.x / 12;     // window 0..799
    const int h = blockIdx.x % 12;     // head
    __shared__ float q[49][33], k[49][33], v[49][33];
    __shared__ float s[49][49];
    __shared__ float brow[49];
    __shared__ int   simg[49];
    const int tid = threadIdx.x;

    if (tid < 49) {
        int b  = w / 25, wi = w % 25;
        int gh = (wi / 5) * 7 + tid / 7;
        int gw = (wi % 5) * 7 + tid % 7;
        simg[tid] = (gh < 32 && gw < 32) ? (b * 1024 + gh * 32 + gw) : -1;
        brow[tid] = attn_bias[h * 49 + tid];
    }
    __syncthreads();

    for (int e = tid; e < 49 * 32; e += 256) {
        int n = e >> 5, d = e & 31;
        int si = simg[n];
        const float* p = (si >= 0) ? (qkv + (size_t)si * N3 + h * 96 + d)
                                   : (padvec + h * 96 + d);
        q[n][d] = p[0];
        k[n][d] = p[32];
        v[n][d] = p[64];
    }
    __syncthreads();

    for (int e = tid; e < 49 * 49; e += 256) {
        int n = e / 49, m = e % 49;
        float acc = 0.f;
        #pragma unroll
        for (int d = 0; d < 32; ++d) acc = fmaf(q[n][d], k[m][d], acc);
        s[n][m] = acc * 0.17677669529663687f + brow[bias_idxs[e]];
    }
    __syncthreads();

    if (tid < 49) {
        float mx = -1e30f;
        for (int m = 0; m < 49; ++m) mx = fmaxf(mx, s[tid][m]);
        float sum = 0.f;
        for (int m = 0; m < 49; ++m) { float e2 = expf(s[tid][m] - mx); s[tid][m] = e2; sum += e2; }
        float inv = 1.f / sum;
        for (int m = 0; m < 49; ++m) s[tid][m] *= inv;
    }
    __syncthreads();

    for (int e = tid; e < 49 * 32; e += 256) {
        int n = e >> 5, d = e & 31;
        int si = simg[n];
        if (si < 0) continue;
        float acc = 0.f;
        for (int m = 0; m < 49; ++m) acc = fmaf(s[n][m], v[m][d], acc);
        o[(size_t)si * CDIM + h * 32 + d] = f2bf(acc);
    }
}

// ---------------- depthwise 3x3 conv (channels-last) + BN (fp32) ----------------
__global__ __launch_bounds__(256) void conv_bn_kernel(
    const float* __restrict__ xin, const float* __restrict__ cw,
    const float* __restrict__ bn_g, const float* __restrict__ bn_b,
    const float* __restrict__ bn_m, const float* __restrict__ bn_v,
    float* __restrict__ xout)
{
    __shared__ float wsm[9 * 384];
    for (int i = threadIdx.x; i < 9 * 384; i += 256) {
        int c = i / 9, wi = i % 9;
        wsm[wi * 384 + c] = cw[i];
    }
    __syncthreads();

    int gid = blockIdx.x * 256 + threadIdx.x;
    int c4 = gid % 96;
    int t  = gid / 96;
    int w  = t % 32; t /= 32;
    int h  = t % 32;
    int b  = t / 32;
    int c0 = c4 * 4;

    float4 acc = make_float4(0.f, 0.f, 0.f, 0.f);
    #pragma unroll
    for (int dh = -1; dh <= 1; ++dh) {
        int hh = h + dh;
        if (hh < 0 || hh >= 32) continue;
        #pragma unroll
        for (int dw = -1; dw <= 1; ++dw) {
            int ww = w + dw;
            if (ww < 0 || ww >= 32) continue;
            float4 xv = *(const float4*)(xin + ((size_t)(b * 1024 + hh * 32 + ww)) * CDIM + c0);
            float4 wv = *(const float4*)&wsm[((dh + 1) * 3 + (dw + 1)) * 384 + c0];
            acc.x = fmaf(xv.x, wv.x, acc.x);
            acc.y = fmaf(xv.y, wv.y, acc.y);
            acc.z = fmaf(xv.z, wv.z, acc.z);
            acc.w = fmaf(xv.w, wv.w, acc.w);
        }
    }
    float4 o;
    float sc;
    sc = rsqrtf(bn_v[c0 + 0] + EPSF) * bn_g[c0 + 0]; o.x = (acc.x - bn_m[c0 + 0]) * sc + bn_b[c0 + 0];
    sc = rsqrtf(bn_v[c0 + 1] + EPSF) * bn_g[c0 + 1]; o.y = (acc.y - bn_m[c0 + 1]) * sc + bn_b[c0 + 1];
    sc = rsqrtf(bn_v[c0 + 2] + EPSF) * bn_g[c0 + 2]; o.z = (acc.z - bn_m[c0 + 2]) * sc + bn_b[c0 + 2];
    sc = rsqrtf(bn_v[c0 + 3] + EPSF) * bn_g[c0 + 3]; o.w = (acc.w - bn_m[c0 + 3]) * sc + bn_b[c0 + 3];
    *(float4*)(xout + (size_t)gid * 4) = o;
}

// ---------------- launch ----------------
extern "C" void kernel_launch(void* const* d_in, const int* in_sizes, int n_in,
                              void* d_out, int out_size, void* d_ws, size_t ws_size,
                              hipStream_t stream) {
    const float* x         = (const float*)d_in[0];
    const float* ln1_w     = (const float*)d_in[1];
    const float* ln1_b     = (const float*)d_in[2];
    const float* qkv_w     = (const float*)d_in[3];
    const float* qkv_b     = (const float*)d_in[4];
    const float* proj_w    = (const float*)d_in[5];
    const float* proj_b    = (const float*)d_in[6];
    const float* attn_bias = (const float*)d_in[7];
    const int*   bias_idxs = (const int*)d_in[8];
    const float* conv_w    = (const float*)d_in[9];
    const float* bn_g      = (const float*)d_in[10];
    const float* bn_b      = (const float*)d_in[11];
    const float* bn_m      = (const float*)d_in[12];
    const float* bn_v      = (const float*)d_in[13];
    const float* ln2_w     = (const float*)d_in[14];
    const float* ln2_b     = (const float*)d_in[15];
    const float* fc1_w     = (const float*)d_in[16];
    const float* fc1_b     = (const float*)d_in[17];
    const float* fc2_w     = (const float*)d_in[18];
    const float* fc2_b     = (const float*)d_in[19];
    float* out = (float*)d_out;

    // workspace ~179.7 MB with lifetime overlays:
    //  R0 [0, 25.2MB):       A1 (LN1 bf16) -> oimg (attn out bf16) -> A2 (LN2 bf16)
    //  R1 [25.2, 176.2MB):   qkvb fp32 -> x1 fp32 -> hbuf bf16
    //  RW [176.2, 179.7MB):  bf16 transposed weights + padvec
    char* ws = (char*)d_ws;
    ushort_t* A1    = (ushort_t*)(ws + 0);              // 32768*384*2  = 25,165,824
    ushort_t* oimg  = (ushort_t*)(ws + 0);
    ushort_t* A2    = (ushort_t*)(ws + 0);
    float*    qkvb  = (float*)(ws + 25165824ULL);       // 32768*1152*4 = 150,994,944
    float*    x1    = (float*)(ws + 25165824ULL);       // 32768*384*4
    ushort_t* hbuf  = (ushort_t*)(ws + 25165824ULL);    // 32768*1536*2 = 100,663,296
    ushort_t* wtqkv = (ushort_t*)(ws + 176160768ULL);   // 1152*384*2 = 884,736
    ushort_t* wtprj = (ushort_t*)(ws + 177045504ULL);   // 384*384*2  = 294,912
    ushort_t* wtfc1 = (ushort_t*)(ws + 177340416ULL);   // 1536*384*2 = 1,179,648
    ushort_t* wtfc2 = (ushort_t*)(ws + 178520064ULL);   // 384*1536*2 = 1,179,648
    float*    pvec  = (float*)(ws + 179699712ULL);      // 4,608

    // 0) weights -> bf16 [N][K]
    wt_bf16_kernel<<<dim3(36, 12), 256, 0, stream>>>(qkv_w,  wtqkv, 384, 1152);
    wt_bf16_kernel<<<dim3(12, 12), 256, 0, stream>>>(proj_w, wtprj, 384, 384);
    wt_bf16_kernel<<<dim3(48, 12), 256, 0, stream>>>(fc1_w,  wtfc1, 384, 1536);
    wt_bf16_kernel<<<dim3(12, 48), 256, 0, stream>>>(fc2_w,  wtfc2, 1536, 384);
    // 1) pad-slot qkv row (fp32)
    padvec_kernel<<<5, 256, 0, stream>>>(ln1_b, qkv_w, qkv_b, pvec);
    // 2) A1 = bf16(LN1(x))
    ln_bf16_kernel<<<8192, 256, 0, stream>>>(x, ln1_w, ln1_b, A1);
    // 3) qkvb = A1 @ wtqkv^T + qkv_b (fp32 out)
    gemm_bf16_kernel<0><<<dim3(9, 256), 256, 0, stream>>>(
        A1, wtqkv, qkv_b, qkvb, nullptr, N3, CDIM);
    // 4) windowed attention -> oimg bf16
    attn_kernel<<<9600, 256, 0, stream>>>(qkvb, pvec, attn_bias, bias_idxs, oimg);
    // 5) x1 = x + oimg @ wtprj^T + proj_b
    gemm_bf16_kernel<2><<<dim3(3, 256), 256, 0, stream>>>(
        oimg, wtprj, proj_b, x1, x, CDIM, CDIM);
    // 6) x2(=d_out) = BN(dwconv3x3(x1))
    conv_bn_kernel<<<12288, 256, 0, stream>>>(x1, conv_w, bn_g, bn_b, bn_m, bn_v, out);
    // 7) A2 = bf16(LN2(x2))
    ln_bf16_kernel<<<8192, 256, 0, stream>>>(out, ln2_w, ln2_b, A2);
    // 8) hbuf = bf16(gelu(A2 @ wtfc1^T + fc1_b))
    gemm_bf16_kernel<1><<<dim3(12, 256), 256, 0, stream>>>(
        A2, wtfc1, fc1_b, hbuf, nullptr, FFDIM, CDIM);
    // 9) out = x2 + hbuf @ wtfc2^T + fc2_b  (in place over d_out)
    gemm_bf16_kernel<2><<<dim3(3, 256), 256, 0, stream>>>(
        hbuf, wtfc2, fc2_b, out, out, CDIM, FFDIM);
}

// Round 4
// 516.878 us; speedup vs baseline: 3.5783x; 1.3214x over previous
//
#include <hip/hip_runtime.h>
#include <math.h>

#define EPSF 1e-5f

// ---- problem dims ----
#define NROW   32768   // B*H*W image tokens
#define CDIM   384
#define N3     1152
#define FFDIM  1536

typedef unsigned short ushort_t;
typedef __attribute__((ext_vector_type(8))) short short8v;   // 8 bf16 (4 VGPRs)
typedef __attribute__((ext_vector_type(4))) float f32x4;     // MFMA accumulator

__device__ __forceinline__ float gelu_exact(float v) {
    return 0.5f * v * (1.f + erff(v * 0.70710678118654752f));
}

// fp32 -> bf16 round-to-nearest-even
__device__ __forceinline__ ushort_t f2bf(float f) {
    union { float f; unsigned u; } v; v.f = f;
    unsigned r = v.u + 0x7fffu + ((v.u >> 16) & 1u);
    return (ushort_t)(r >> 16);
}

// ---------------- weight transpose + bf16 convert: W[K][N] -> Wt[N][K] ----------------
__global__ __launch_bounds__(256) void wt_bf16_kernel(const float* __restrict__ W,
                                                      ushort_t* __restrict__ Wt,
                                                      int K, int N) {
    __shared__ float t[32][33];
    const int bx = blockIdx.x, by = blockIdx.y;       // n-tile, k-tile
    const int c = threadIdx.x & 31, r0 = threadIdx.x >> 5;
    #pragma unroll
    for (int i = 0; i < 4; ++i) {
        int r = r0 + i * 8;
        t[r][c] = W[(size_t)(by * 32 + r) * N + bx * 32 + c];
    }
    __syncthreads();
    #pragma unroll
    for (int i = 0; i < 4; ++i) {
        int r = r0 + i * 8;
        Wt[(size_t)(bx * 32 + r) * K + by * 32 + c] = f2bf(t[c][r]);
    }
}

// ---------------- padvec: qkv row of a zero-padded token (bf16 out) ----------------
__global__ __launch_bounds__(256) void padvec_kernel(
    const float* __restrict__ ln1_b, const float* __restrict__ qkv_w,
    const float* __restrict__ qkv_b, ushort_t* __restrict__ padvec)
{
    int j = blockIdx.x * 256 + threadIdx.x;
    if (j >= N3) return;
    float acc = qkv_b[j];
    for (int k = 0; k < CDIM; ++k) acc = fmaf(ln1_b[k], qkv_w[k * N3 + j], acc);
    padvec[j] = f2bf(acc);
}

// ---------------- fused LN (stats + normalize) -> bf16 rows, one wave/row ----------------
__global__ __launch_bounds__(256) void ln_bf16_kernel(
    const float* __restrict__ src, const float* __restrict__ w,
    const float* __restrict__ b, ushort_t* __restrict__ dst)
{
    const int row  = blockIdx.x * 4 + (threadIdx.x >> 6);
    const int lane = threadIdx.x & 63;
    const float* p = src + (size_t)row * CDIM;
    float vals[6];
    float s1 = 0.f, s2 = 0.f;
    #pragma unroll
    for (int i = 0; i < 6; ++i) {
        float v = p[lane + 64 * i];
        vals[i] = v; s1 += v; s2 += v * v;
    }
    #pragma unroll
    for (int off = 32; off > 0; off >>= 1) {
        s1 += __shfl_xor(s1, off);
        s2 += __shfl_xor(s2, off);
    }
    float mu = s1 * (1.f / CDIM);
    float rs = rsqrtf(s2 * (1.f / CDIM) - mu * mu + EPSF);
    ushort_t* q = dst + (size_t)row * CDIM;
    #pragma unroll
    for (int i = 0; i < 6; ++i) {
        int k = lane + 64 * i;
        q[k] = f2bf((vals[i] - mu) * rs * w[k] + b[k]);
    }
}

// ---------------- bf16 MFMA GEMM: C = A[M][K] @ Bt[N][K]^T, 128x128 tile ----------------
// EPI: 0 = +bias, bf16 store (qkv)
//      1 = +bias, gelu, bf16 store (fc1)
//      2 = +bias, +resid, fp32 store (proj, fc2)
template<int EPI>
__global__ __launch_bounds__(256) void gemm_bf16_kernel(
    const ushort_t* __restrict__ A, const ushort_t* __restrict__ Bt,
    const float* __restrict__ bias, void* __restrict__ outv,
    const float* __restrict__ resid, int Nn, int K)
{
    __shared__ ushort_t As[128][72];   // +8 pad: 144B row stride -> benign aliasing
    __shared__ ushort_t Bs[128][72];
    const int tid  = threadIdx.x;
    const int lane = tid & 63;
    const int wv   = tid >> 6;
    const int wm   = (wv & 1) * 64, wn = (wv >> 1) * 64;
    const int bn0  = blockIdx.x * 128, bm0 = blockIdx.y * 128;

    const int srow = tid >> 3;     // staging: base row 0..31
    const int skc  = tid & 7;      // 16B chunk within row (8 bf16)

    f32x4 acc[4][4] = {};

    const int cl = lane & 15;
    const int kq = (lane >> 4) * 8;

    for (int kt = 0; kt < K; kt += 64) {
        if (kt) __syncthreads();
        #pragma unroll
        for (int i = 0; i < 4; ++i) {
            int row = srow + i * 32;
            *(float4*)&As[row][skc * 8] =
                *(const float4*)(A  + (size_t)(bm0 + row) * K + kt + skc * 8);
            *(float4*)&Bs[row][skc * 8] =
                *(const float4*)(Bt + (size_t)(bn0 + row) * K + kt + skc * 8);
        }
        __syncthreads();
        #pragma unroll
        for (int kb = 0; kb < 2; ++kb) {
            const int ko = kb * 32 + kq;
            short8v a[4], b[4];
            #pragma unroll
            for (int mi = 0; mi < 4; ++mi)
                a[mi] = *(const short8v*)&As[wm + mi * 16 + cl][ko];
            #pragma unroll
            for (int ni = 0; ni < 4; ++ni)
                b[ni] = *(const short8v*)&Bs[wn + ni * 16 + cl][ko];
            #pragma unroll
            for (int mi = 0; mi < 4; ++mi)
                #pragma unroll
                for (int ni = 0; ni < 4; ++ni)
                    acc[mi][ni] = __builtin_amdgcn_mfma_f32_16x16x32_bf16(
                        a[mi], b[ni], acc[mi][ni], 0, 0, 0);
        }
    }

    // epilogue: D col = lane&15, row = (lane>>4)*4 + reg
    const int rq = (lane >> 4) * 4;
    #pragma unroll
    for (int ni = 0; ni < 4; ++ni) {
        const int col = bn0 + wn + ni * 16 + cl;
        const float bs = bias[col];
        #pragma unroll
        for (int mi = 0; mi < 4; ++mi) {
            const int row = bm0 + wm + mi * 16 + rq;
            #pragma unroll
            for (int r = 0; r < 4; ++r) {
                float v = acc[mi][ni][r] + bs;
                size_t off = (size_t)(row + r) * Nn + col;
                if (EPI == 0) {
                    ((ushort_t*)outv)[off] = f2bf(v);
                } else if (EPI == 1) {
                    ((ushort_t*)outv)[off] = f2bf(gelu_exact(v));
                } else {
                    ((float*)outv)[off] = v + resid[off];
                }
            }
        }
    }
}

// ---------------- MFMA window attention: one block per (window, head) ----------------
// qkv bf16 image layout. S^T = mfma(K, Q) -> in-register softmax (per-lane 16 vals
// + 2 shfl_xor) -> P bf16 to LDS -> O = mfma(P, Vt) -> bf16 scatter.
__global__ __launch_bounds__(256) void attn_kernel(
    const ushort_t* __restrict__ qkv, const ushort_t* __restrict__ padvec,
    const float* __restrict__ attn_bias, const int* __restrict__ bias_idxs,
    ushort_t* __restrict__ o)
{
    const int w = blockIdx.x / 12;     // window 0..799
    const int h = blockIdx.x % 12;     // head
    __shared__ ushort_t Qs[64][40];    // [token][d], 80B stride
    __shared__ ushort_t Ks[64][40];
    __shared__ ushort_t Vts[32][72];   // [d][token], 144B stride (16B-aligned rows)
    __shared__ ushort_t Ps[64][72];    // [query][key]
    __shared__ float    browl[49];
    __shared__ int      simgl[49];
    const int tid  = threadIdx.x;
    const int lane = tid & 63;
    const int wv   = tid >> 6;
    const int cl   = lane & 15;
    const int lg   = lane >> 4;

    if (tid < 49) {
        int b  = w / 25, wi = w % 25;
        int gh = (wi / 5) * 7 + tid / 7;
        int gw = (wi % 5) * 7 + tid % 7;
        simgl[tid] = (gh < 32 && gw < 32) ? (b * 1024 + gh * 32 + gw) : -1;
        browl[tid] = attn_bias[h * 49 + tid];
    }

    // stage Q,K ([token][d]) and V transposed ([d][token]); t>=49 zeroed
    for (int e = tid; e < 64 * 12; e += 256) {
        int t = e / 12, j = e % 12;
        uint4 val = make_uint4(0u, 0u, 0u, 0u);
        if (t < 49) {
            int b  = w / 25, wi = w % 25;
            int gh = (wi / 5) * 7 + t / 7;
            int gw = (wi % 5) * 7 + t % 7;
            const ushort_t* src = (gh < 32 && gw < 32)
                ? qkv + (size_t)(b * 1024 + gh * 32 + gw) * N3 + h * 96 + j * 8
                : padvec + h * 96 + j * 8;
            val = *(const uint4*)src;
        }
        if (j < 4)      *(uint4*)&Qs[t][j * 8] = val;
        else if (j < 8) *(uint4*)&Ks[t][(j - 4) * 8] = val;
        else {
            int d0 = (j - 8) * 8;
            unsigned uu[4] = {val.x, val.y, val.z, val.w};
            #pragma unroll
            for (int ii = 0; ii < 4; ++ii) {
                Vts[d0 + 2 * ii + 0][t] = (ushort_t)(uu[ii] & 0xffffu);
                Vts[d0 + 2 * ii + 1][t] = (ushort_t)(uu[ii] >> 16);
            }
        }
    }
    __syncthreads();

    // ---- S^T = K @ Q^T: A=K rows(keys), B=Q cols(queries = wave's 16) ----
    const int q = wv * 16 + cl;       // this lane's query column
    short8v qf = *(const short8v*)&Qs[q][lg * 8];
    f32x4 st[4];
    #pragma unroll
    for (int mi = 0; mi < 4; ++mi) {
        short8v kf = *(const short8v*)&Ks[mi * 16 + cl][lg * 8];
        f32x4 z = {};
        st[mi] = __builtin_amdgcn_mfma_f32_16x16x32_bf16(kf, qf, z, 0, 0, 0);
    }

    // ---- bias + in-register softmax over keys (column q) ----
    float sv[4][4];
    float m = -1e30f;
    #pragma unroll
    for (int mi = 0; mi < 4; ++mi)
        #pragma unroll
        for (int r = 0; r < 4; ++r) {
            int key = mi * 16 + lg * 4 + r;
            float bb = (q < 49 && key < 49)
                     ? browl[bias_idxs[q * 49 + key]] : -1e30f;
            float s = st[mi][r] * 0.17677669529663687f + bb;
            sv[mi][r] = s;
            m = fmaxf(m, s);
        }
    m = fmaxf(m, __shfl_xor(m, 16));
    m = fmaxf(m, __shfl_xor(m, 32));
    float sum = 0.f;
    #pragma unroll
    for (int mi = 0; mi < 4; ++mi)
        #pragma unroll
        for (int r = 0; r < 4; ++r) {
            float p = __expf(sv[mi][r] - m);
            sv[mi][r] = p;
            sum += p;
        }
    sum += __shfl_xor(sum, 16);
    sum += __shfl_xor(sum, 32);
    const float inv = 1.f / sum;

    // ---- P -> LDS (wave-local query rows; no barrier needed) ----
    #pragma unroll
    for (int mi = 0; mi < 4; ++mi) {
        uint2 pk;
        pk.x = (unsigned)f2bf(sv[mi][0] * inv) | ((unsigned)f2bf(sv[mi][1] * inv) << 16);
        pk.y = (unsigned)f2bf(sv[mi][2] * inv) | ((unsigned)f2bf(sv[mi][3] * inv) << 16);
        *(uint2*)&Ps[q][mi * 16 + lg * 4] = pk;
    }

    // ---- O = P @ V: A=P rows(queries), B=Vt cols(d) ----
    f32x4 oacc[2] = {};
    #pragma unroll
    for (int kb = 0; kb < 2; ++kb) {
        short8v pa = *(const short8v*)&Ps[q][kb * 32 + lg * 8];
        #pragma unroll
        for (int ni = 0; ni < 2; ++ni) {
            short8v vb = *(const short8v*)&Vts[ni * 16 + cl][kb * 32 + lg * 8];
            oacc[ni] = __builtin_amdgcn_mfma_f32_16x16x32_bf16(pa, vb, oacc[ni], 0, 0, 0);
        }
    }

    // ---- scatter: D col = d, row = query ----
    #pragma unroll
    for (int ni = 0; ni < 2; ++ni) {
        int d = h * 32 + ni * 16 + cl;
        #pragma unroll
        for (int r = 0; r < 4; ++r) {
            int q2 = wv * 16 + lg * 4 + r;
            if (q2 < 49) {
                int si = simgl[q2];
                if (si >= 0) o[(size_t)si * CDIM + d] = f2bf(oacc[ni][r]);
            }
        }
    }
}

// ---------------- depthwise 3x3 conv (channels-last) + BN (fp32) ----------------
__global__ __launch_bounds__(256) void conv_bn_kernel(
    const float* __restrict__ xin, const float* __restrict__ cw,
    const float* __restrict__ bn_g, const float* __restrict__ bn_b,
    const float* __restrict__ bn_m, const float* __restrict__ bn_v,
    float* __restrict__ xout)
{
    __shared__ float wsm[9 * 384];
    for (int i = threadIdx.x; i < 9 * 384; i += 256) {
        int c = i / 9, wi = i % 9;
        wsm[wi * 384 + c] = cw[i];
    }
    __syncthreads();

    int gid = blockIdx.x * 256 + threadIdx.x;
    int c4 = gid % 96;
    int t  = gid / 96;
    int w  = t % 32; t /= 32;
    int h  = t % 32;
    int b  = t / 32;
    int c0 = c4 * 4;

    float4 acc = make_float4(0.f, 0.f, 0.f, 0.f);
    #pragma unroll
    for (int dh = -1; dh <= 1; ++dh) {
        int hh = h + dh;
        if (hh < 0 || hh >= 32) continue;
        #pragma unroll
        for (int dw = -1; dw <= 1; ++dw) {
            int ww = w + dw;
            if (ww < 0 || ww >= 32) continue;
            float4 xv = *(const float4*)(xin + ((size_t)(b * 1024 + hh * 32 + ww)) * CDIM + c0);
            float4 wv = *(const float4*)&wsm[((dh + 1) * 3 + (dw + 1)) * 384 + c0];
            acc.x = fmaf(xv.x, wv.x, acc.x);
            acc.y = fmaf(xv.y, wv.y, acc.y);
            acc.z = fmaf(xv.z, wv.z, acc.z);
            acc.w = fmaf(xv.w, wv.w, acc.w);
        }
    }
    float4 o;
    float sc;
    sc = rsqrtf(bn_v[c0 + 0] + EPSF) * bn_g[c0 + 0]; o.x = (acc.x - bn_m[c0 + 0]) * sc + bn_b[c0 + 0];
    sc = rsqrtf(bn_v[c0 + 1] + EPSF) * bn_g[c0 + 1]; o.y = (acc.y - bn_m[c0 + 1]) * sc + bn_b[c0 + 1];
    sc = rsqrtf(bn_v[c0 + 2] + EPSF) * bn_g[c0 + 2]; o.z = (acc.z - bn_m[c0 + 2]) * sc + bn_b[c0 + 2];
    sc = rsqrtf(bn_v[c0 + 3] + EPSF) * bn_g[c0 + 3]; o.w = (acc.w - bn_m[c0 + 3]) * sc + bn_b[c0 + 3];
    *(float4*)(xout + (size_t)gid * 4) = o;
}

// ---------------- launch ----------------
extern "C" void kernel_launch(void* const* d_in, const int* in_sizes, int n_in,
                              void* d_out, int out_size, void* d_ws, size_t ws_size,
                              hipStream_t stream) {
    const float* x         = (const float*)d_in[0];
    const float* ln1_w     = (const float*)d_in[1];
    const float* ln1_b     = (const float*)d_in[2];
    const float* qkv_w     = (const float*)d_in[3];
    const float* qkv_b     = (const float*)d_in[4];
    const float* proj_w    = (const float*)d_in[5];
    const float* proj_b    = (const float*)d_in[6];
    const float* attn_bias = (const float*)d_in[7];
    const int*   bias_idxs = (const int*)d_in[8];
    const float* conv_w    = (const float*)d_in[9];
    const float* bn_g      = (const float*)d_in[10];
    const float* bn_b      = (const float*)d_in[11];
    const float* bn_m      = (const float*)d_in[12];
    const float* bn_v      = (const float*)d_in[13];
    const float* ln2_w     = (const float*)d_in[14];
    const float* ln2_b     = (const float*)d_in[15];
    const float* fc1_w     = (const float*)d_in[16];
    const float* fc1_b     = (const float*)d_in[17];
    const float* fc2_w     = (const float*)d_in[18];
    const float* fc2_b     = (const float*)d_in[19];
    float* out = (float*)d_out;

    // workspace with lifetime overlays:
    //  R0 [0, 25.2MB):       A1 (LN1 bf16) -> oimg (attn out bf16) -> A2 (LN2 bf16)
    //  R1 [25.2, 176.2MB):   qkvb bf16 (75.5MB) -> x1 fp32 (50.3MB) -> hbuf bf16 (100.7MB)
    //  RW [176.2, ...):      bf16 transposed weights + padvec
    char* ws = (char*)d_ws;
    ushort_t* A1    = (ushort_t*)(ws + 0);              // 32768*384*2  = 25,165,824
    ushort_t* oimg  = (ushort_t*)(ws + 0);
    ushort_t* A2    = (ushort_t*)(ws + 0);
    ushort_t* qkvb  = (ushort_t*)(ws + 25165824ULL);    // 32768*1152*2 = 75,497,472
    float*    x1    = (float*)(ws + 25165824ULL);       // 32768*384*4
    ushort_t* hbuf  = (ushort_t*)(ws + 25165824ULL);    // 32768*1536*2 = 100,663,296
    ushort_t* wtqkv = (ushort_t*)(ws + 176160768ULL);   // 1152*384*2 = 884,736
    ushort_t* wtprj = (ushort_t*)(ws + 177045504ULL);   // 384*384*2  = 294,912
    ushort_t* wtfc1 = (ushort_t*)(ws + 177340416ULL);   // 1536*384*2 = 1,179,648
    ushort_t* wtfc2 = (ushort_t*)(ws + 178520064ULL);   // 384*1536*2 = 1,179,648
    ushort_t* pvec  = (ushort_t*)(ws + 179699712ULL);   // 2,304

    // 0) weights -> bf16 [N][K]
    wt_bf16_kernel<<<dim3(36, 12), 256, 0, stream>>>(qkv_w,  wtqkv, 384, 1152);
    wt_bf16_kernel<<<dim3(12, 12), 256, 0, stream>>>(proj_w, wtprj, 384, 384);
    wt_bf16_kernel<<<dim3(48, 12), 256, 0, stream>>>(fc1_w,  wtfc1, 384, 1536);
    wt_bf16_kernel<<<dim3(12, 48), 256, 0, stream>>>(fc2_w,  wtfc2, 1536, 384);
    // 1) pad-slot qkv row (bf16)
    padvec_kernel<<<5, 256, 0, stream>>>(ln1_b, qkv_w, qkv_b, pvec);
    // 2) A1 = bf16(LN1(x))
    ln_bf16_kernel<<<8192, 256, 0, stream>>>(x, ln1_w, ln1_b, A1);
    // 3) qkvb = A1 @ wtqkv^T + qkv_b (bf16 out)
    gemm_bf16_kernel<0><<<dim3(9, 256), 256, 0, stream>>>(
        A1, wtqkv, qkv_b, qkvb, nullptr, N3, CDIM);
    // 4) MFMA windowed attention -> oimg bf16
    attn_kernel<<<9600, 256, 0, stream>>>(qkvb, pvec, attn_bias, bias_idxs, oimg);
    // 5) x1 = x + oimg @ wtprj^T + proj_b
    gemm_bf16_kernel<2><<<dim3(3, 256), 256, 0, stream>>>(
        oimg, wtprj, proj_b, x1, x, CDIM, CDIM);
    // 6) x2(=d_out) = BN(dwconv3x3(x1))
    conv_bn_kernel<<<12288, 256, 0, stream>>>(x1, conv_w, bn_g, bn_b, bn_m, bn_v, out);
    // 7) A2 = bf16(LN2(x2))
    ln_bf16_kernel<<<8192, 256, 0, stream>>>(out, ln2_w, ln2_b, A2);
    // 8) hbuf = bf16(gelu(A2 @ wtfc1^T + fc1_b))
    gemm_bf16_kernel<1><<<dim3(12, 256), 256, 0, stream>>>(
        A2, wtfc1, fc1_b, hbuf, nullptr, FFDIM, CDIM);
    // 9) out = x2 + hbuf @ wtfc2^T + fc2_b  (in place over d_out)
    gemm_bf16_kernel<2><<<dim3(3, 256), 256, 0, stream>>>(
        hbuf, wtfc2, fc2_b, out, out, CDIM, FFDIM);
}